// Round 1
// baseline (979.949 us; speedup 1.0000x reference)
//
#include <hip/hip_runtime.h>
#include <math.h>

#define NB 4
#define NS 2048
#define ND 256
#define NH 8
#define NHD 32
#define NFF 1024
#define NM (NB*NS)   // 8192
#define PADK 36      // LDS row stride (floats): 16B-aligned, conflict-free for per-row float4

__device__ __forceinline__ float wsum(float v){
  #pragma unroll
  for(int o=32;o>0;o>>=1) v += __shfl_xor(v,o);
  return v;
}
__device__ __forceinline__ float wmax(float v){
  #pragma unroll
  for(int o=32;o>0;o>>=1) v = fmaxf(v,__shfl_xor(v,o));
  return v;
}

// ---------------- QKV projection: Q/K/V = src @ W^T + b ----------------
__global__ __launch_bounds__(256) void qkv_kernel(
    const float* __restrict__ src,
    const float* __restrict__ Wq, const float* __restrict__ bq,
    const float* __restrict__ Wk, const float* __restrict__ bk,
    const float* __restrict__ Wv, const float* __restrict__ bv,
    float* __restrict__ Q, float* __restrict__ K, float* __restrict__ V){
  __shared__ float a[8][ND];
  const int t = threadIdx.x;
  const int m0 = blockIdx.x*8;
  #pragma unroll
  for(int r=0;r<8;r++) a[r][t] = src[(size_t)(m0+r)*ND + t];
  __syncthreads();
  float aq[8], ak[8], av[8];
  #pragma unroll
  for(int r=0;r<8;r++){ aq[r]=bq[t]; ak[r]=bk[t]; av[r]=bv[t]; }
  const float4* wq = (const float4*)(Wq + (size_t)t*ND);
  const float4* wk = (const float4*)(Wk + (size_t)t*ND);
  const float4* wv = (const float4*)(Wv + (size_t)t*ND);
  for(int k4=0;k4<ND/4;k4++){
    float4 q4 = wq[k4], k4v = wk[k4], v4 = wv[k4];
    #pragma unroll
    for(int r=0;r<8;r++){
      float4 a4 = *(const float4*)&a[r][k4*4];
      aq[r] += a4.x*q4.x + a4.y*q4.y + a4.z*q4.z + a4.w*q4.w;
      ak[r] += a4.x*k4v.x + a4.y*k4v.y + a4.z*k4v.z + a4.w*k4v.w;
      av[r] += a4.x*v4.x + a4.y*v4.y + a4.z*v4.z + a4.w*v4.w;
    }
  }
  #pragma unroll
  for(int r=0;r<8;r++){
    size_t o = (size_t)(m0+r)*ND + t;
    Q[o]=aq[r]; K[o]=ak[r]; V[o]=av[r];
  }
}

// ---------------- causal flash attention, one wave per query row ----------------
__global__ __launch_bounds__(256) void attn_kernel(
    const float* __restrict__ Q, const float* __restrict__ K, const float* __restrict__ V,
    float* __restrict__ AO){
  __shared__ float kt[64*PADK];
  __shared__ float vt[64*PADK];
  __shared__ float red[64*PADK];
  const int t = threadIdx.x;
  const int lane = t & 63;
  const int wv_ = t >> 6;
  const int i0 = (blockIdx.x & (NS/4 - 1))*4;   // 4 consecutive rows per block
  const int bh = blockIdx.x >> 9;               // NS/4 = 512
  const int b = bh >> 3, h = bh & 7;
  const int i = i0 + wv_;
  const float scale = 0.17677669529663687f;     // 1/sqrt(32)
  const float* qp = Q + ((size_t)(b*NS + i))*ND + h*NHD;
  float q[NHD];
  #pragma unroll
  for(int d=0; d<NHD; d++) q[d] = qp[d]*scale;
  float acc[NHD];
  #pragma unroll
  for(int d=0; d<NHD; d++) acc[d]=0.f;
  float m = -INFINITY, l = 0.f;
  const float* Kb = K + ((size_t)(b*NS))*ND + h*NHD;
  const float* Vb = V + ((size_t)(b*NS))*ND + h*NHD;
  const int imax = i0 + 3;
  for(int jt=0; jt<=imax; jt+=64){
    // cooperative stage of 64 K rows + 64 V rows (each row = 8 float4)
    #pragma unroll
    for(int it=0; it<2; it++){
      int idx = it*256 + t;          // 0..511 float4 units
      int j = idx>>3, f = idx&7;
      *(float4*)&kt[j*PADK + f*4] = *(const float4*)(Kb + (size_t)(jt+j)*ND + f*4);
      *(float4*)&vt[j*PADK + f*4] = *(const float4*)(Vb + (size_t)(jt+j)*ND + f*4);
    }
    __syncthreads();
    float s = 0.f;
    const float* kr = &kt[lane*PADK];
    #pragma unroll
    for(int f=0; f<8; f++){
      float4 k4 = *(const float4*)&kr[f*4];
      s += q[f*4+0]*k4.x + q[f*4+1]*k4.y + q[f*4+2]*k4.z + q[f*4+3]*k4.w;
    }
    if((jt + lane) > i) s = -INFINITY;
    float tmax = wmax(s);
    if(tmax > m){                      // wave-uniform rescale only when max grows
      float sc = expf(m - tmax);       // first time: exp(-inf)=0, zeroes the empty state
      m = tmax;
      l *= sc;
      #pragma unroll
      for(int d=0; d<NHD; d++) acc[d]*=sc;
    }
    float p = expf(s - m);             // invalid lanes: exp(-inf - m) = 0
    l += p;
    const float* vr = &vt[lane*PADK];
    #pragma unroll
    for(int f=0; f<8; f++){
      float4 v4 = *(const float4*)&vr[f*4];
      acc[f*4+0] += p*v4.x; acc[f*4+1] += p*v4.y;
      acc[f*4+2] += p*v4.z; acc[f*4+3] += p*v4.w;
    }
    __syncthreads();
  }
  float lt = wsum(l);
  float inv = 1.f/lt;
  float* op = AO + ((size_t)(b*NS + i))*ND + h*NHD;
  // 4-phase cross-lane reduce of acc (each wave owns one output row)
  for(int w=0; w<4; w++){
    if(wv_==w){
      #pragma unroll
      for(int f=0; f<8; f++)
        *(float4*)&red[lane*PADK + f*4] =
            make_float4(acc[f*4],acc[f*4+1],acc[f*4+2],acc[f*4+3]);
    }
    __syncthreads();
    if(wv_==w){
      int d = lane & 31, p2 = lane >> 5;
      float sum2 = 0.f;
      #pragma unroll
      for(int r=0;r<32;r++) sum2 += red[(p2*32+r)*PADK + d];
      sum2 += __shfl_xor(sum2, 32);
      if(lane < 32) op[d] = sum2 * inv;
    }
    __syncthreads();
  }
}

// ---------------- O-projection + residual + LayerNorm1 ----------------
__global__ __launch_bounds__(256) void oln_kernel(
    const float* __restrict__ AO, const float* __restrict__ Wo, const float* __restrict__ bo,
    const float* __restrict__ src, const float* __restrict__ g1, const float* __restrict__ be1,
    float* __restrict__ S2){
  __shared__ float a[16][ND];
  __shared__ float c[16][ND];
  const int t = threadIdx.x;
  const int m0 = blockIdx.x*16;
  #pragma unroll
  for(int r=0;r<16;r++) a[r][t] = AO[(size_t)(m0+r)*ND + t];
  __syncthreads();
  float acc[16];
  #pragma unroll
  for(int r=0;r<16;r++) acc[r] = bo[t];
  const float4* w = (const float4*)(Wo + (size_t)t*ND);
  for(int k4=0;k4<ND/4;k4++){
    float4 w4 = w[k4];
    #pragma unroll
    for(int r=0;r<16;r++){
      float4 a4 = *(const float4*)&a[r][k4*4];
      acc[r] += a4.x*w4.x + a4.y*w4.y + a4.z*w4.z + a4.w*w4.w;
    }
  }
  #pragma unroll
  for(int r=0;r<16;r++) c[r][t] = acc[r] + src[(size_t)(m0+r)*ND + t];
  __syncthreads();
  const int lane = t&63, wv_ = t>>6;
  #pragma unroll
  for(int rr=0; rr<4; rr++){
    int r = wv_*4+rr;
    float x[4]; float s=0.f, qq=0.f;
    #pragma unroll
    for(int k=0;k<4;k++){ x[k]=c[r][lane+64*k]; s+=x[k]; qq+=x[k]*x[k]; }
    s = wsum(s); qq = wsum(qq);
    float mean = s*(1.f/ND);
    float var = qq*(1.f/ND) - mean*mean;
    float rstd = rsqrtf(var + 1e-5f);
    #pragma unroll
    for(int k=0;k<4;k++){
      int col = lane+64*k;
      S2[(size_t)(m0+r)*ND+col] = (x[k]-mean)*rstd*g1[col] + be1[col];
    }
  }
}

// ---------------- FFN1 + exact GELU ----------------
__global__ __launch_bounds__(256) void ffn1_kernel(
    const float* __restrict__ S2, const float* __restrict__ W1, const float* __restrict__ b1,
    float* __restrict__ FFo){
  __shared__ float a[16][ND];
  const int t = threadIdx.x;
  const int m0 = blockIdx.x*16;
  #pragma unroll
  for(int r=0;r<16;r++) a[r][t] = S2[(size_t)(m0+r)*ND + t];
  __syncthreads();
  float acc[4][16];
  #pragma unroll
  for(int cc=0;cc<4;cc++){
    float bb = b1[t + 256*cc];
    #pragma unroll
    for(int r=0;r<16;r++) acc[cc][r] = bb;
  }
  const float4* w0 = (const float4*)(W1 + (size_t)(t+  0)*ND);
  const float4* w1 = (const float4*)(W1 + (size_t)(t+256)*ND);
  const float4* w2 = (const float4*)(W1 + (size_t)(t+512)*ND);
  const float4* w3 = (const float4*)(W1 + (size_t)(t+768)*ND);
  for(int k4=0;k4<ND/4;k4++){
    float4 c0=w0[k4], c1=w1[k4], c2=w2[k4], c3=w3[k4];
    #pragma unroll
    for(int r=0;r<16;r++){
      float4 a4 = *(const float4*)&a[r][k4*4];
      acc[0][r] += a4.x*c0.x + a4.y*c0.y + a4.z*c0.z + a4.w*c0.w;
      acc[1][r] += a4.x*c1.x + a4.y*c1.y + a4.z*c1.z + a4.w*c1.w;
      acc[2][r] += a4.x*c2.x + a4.y*c2.y + a4.z*c2.z + a4.w*c2.w;
      acc[3][r] += a4.x*c3.x + a4.y*c3.y + a4.z*c3.z + a4.w*c3.w;
    }
  }
  #pragma unroll
  for(int cc=0;cc<4;cc++){
    int col = t + 256*cc;
    #pragma unroll
    for(int r=0;r<16;r++){
      float x = acc[cc][r];
      FFo[(size_t)(m0+r)*NFF + col] = 0.5f*x*(1.f+erff(x*0.70710678118654752f));
    }
  }
}

// ---------------- FFN2 + residual + LayerNorm2 ----------------
__global__ __launch_bounds__(256) void ffn2_kernel(
    const float* __restrict__ FFo, const float* __restrict__ W2, const float* __restrict__ b2,
    const float* __restrict__ S2, const float* __restrict__ g2, const float* __restrict__ be2,
    float* __restrict__ out){
  __shared__ float a[16][ND];
  __shared__ float c[16][ND];
  const int t = threadIdx.x;
  const int m0 = blockIdx.x*16;
  float acc[16];
  #pragma unroll
  for(int r=0;r<16;r++) acc[r] = b2[t];
  for(int kc=0; kc<4; kc++){
    __syncthreads();
    #pragma unroll
    for(int r=0;r<16;r++) a[r][t] = FFo[(size_t)(m0+r)*NFF + kc*256 + t];
    __syncthreads();
    const float4* w = (const float4*)(W2 + (size_t)t*NFF + kc*256);
    for(int k4=0;k4<64;k4++){
      float4 w4 = w[k4];
      #pragma unroll
      for(int r=0;r<16;r++){
        float4 a4 = *(const float4*)&a[r][k4*4];
        acc[r] += a4.x*w4.x + a4.y*w4.y + a4.z*w4.z + a4.w*w4.w;
      }
    }
  }
  #pragma unroll
  for(int r=0;r<16;r++) c[r][t] = acc[r] + S2[(size_t)(m0+r)*ND + t];
  __syncthreads();
  const int lane = t&63, wv_ = t>>6;
  #pragma unroll
  for(int rr=0; rr<4; rr++){
    int r = wv_*4+rr;
    float x[4]; float s=0.f, qq=0.f;
    #pragma unroll
    for(int k=0;k<4;k++){ x[k]=c[r][lane+64*k]; s+=x[k]; qq+=x[k]*x[k]; }
    s = wsum(s); qq = wsum(qq);
    float mean = s*(1.f/ND);
    float var = qq*(1.f/ND) - mean*mean;
    float rstd = rsqrtf(var + 1e-5f);
    #pragma unroll
    for(int k=0;k<4;k++){
      int col = lane+64*k;
      out[(size_t)(m0+r)*ND+col] = (x[k]-mean)*rstd*g2[col] + be2[col];
    }
  }
}

extern "C" void kernel_launch(void* const* d_in, const int* in_sizes, int n_in,
                              void* d_out, int out_size, void* d_ws, size_t ws_size,
                              hipStream_t stream){
  const float* src = (const float*)d_in[0];
  const float* Wq  = (const float*)d_in[1];
  const float* bq  = (const float*)d_in[2];
  const float* Wk  = (const float*)d_in[3];
  const float* bk  = (const float*)d_in[4];
  const float* Wv  = (const float*)d_in[5];
  const float* bv  = (const float*)d_in[6];
  const float* Wo  = (const float*)d_in[7];
  const float* bo  = (const float*)d_in[8];
  const float* W1  = (const float*)d_in[9];
  const float* b1  = (const float*)d_in[10];
  const float* W2  = (const float*)d_in[11];
  const float* b2  = (const float*)d_in[12];
  const float* g1  = (const float*)d_in[13];
  const float* be1 = (const float*)d_in[14];
  const float* g2  = (const float*)d_in[15];
  const float* be2 = (const float*)d_in[16];
  // len_m1 (d_in[17]) is redundant: the prefix-global mask term is implied by causal.

  float* ws = (float*)d_ws;
  const size_t SZ = (size_t)NM*ND;   // 2,097,152 floats
  float* Q  = ws;
  float* K  = Q  + SZ;
  float* V  = K  + SZ;
  float* AO = V  + SZ;
  float* S2 = AO + SZ;
  float* FF = S2 + SZ;               // NM*NFF floats
  float* out = (float*)d_out;

  qkv_kernel <<<NM/8, 256, 0, stream>>>(src, Wq,bq, Wk,bk, Wv,bv, Q,K,V);
  attn_kernel<<<NB*NH*NS/4, 256, 0, stream>>>(Q, K, V, AO);
  oln_kernel <<<NM/16, 256, 0, stream>>>(AO, Wo, bo, src, g1, be1, S2);
  ffn1_kernel<<<NM/16, 256, 0, stream>>>(S2, W1, b1, FF);
  ffn2_kernel<<<NM/16, 256, 0, stream>>>(FF, W2, b2, S2, g2, be2, out);
}

// Round 3
// 513.992 us; speedup vs baseline: 1.9065x; 1.9065x over previous
//
#include <hip/hip_runtime.h>
#include <math.h>

#define NB 4
#define NS 2048
#define ND 256
#define NH 8
#define NHD 32
#define NFF 1024
#define NM (NB*NS)   // 8192
#define KPAD 40      // bf16 elems per K-tile row in LDS (80B stride: bank-floor)
#define VTP 72       // Vt/Plds row stride in bf16 elems (144B: bank-floor)
// qkv Q pre-scale: (1/sqrt(32)) * log2(e)  -> softmax uses exp2
#define QSCALE 0.2550181657f

typedef __attribute__((ext_vector_type(4))) short short4v;
typedef __attribute__((ext_vector_type(8))) short short8v;
typedef __attribute__((ext_vector_type(4))) float f32x4;

__device__ __forceinline__ unsigned short f2bf(float f){
  union { float f; unsigned u; } c; c.f = f;
  unsigned u = c.u + 0x7fffu + ((c.u >> 16) & 1u);   // RNE
  return (unsigned short)(u >> 16);
}

__device__ __forceinline__ float wsum(float v){
  #pragma unroll
  for(int o=32;o>0;o>>=1) v += __shfl_xor(v,o);
  return v;
}

// ---------------- QKV projection: Q/K/V = src @ W^T + b  (bf16 out, Q pre-scaled) ----------------
__global__ __launch_bounds__(256) void qkv_kernel(
    const float* __restrict__ src,
    const float* __restrict__ Wq, const float* __restrict__ bq,
    const float* __restrict__ Wk, const float* __restrict__ bk,
    const float* __restrict__ Wv, const float* __restrict__ bv,
    unsigned short* __restrict__ Q, unsigned short* __restrict__ K, unsigned short* __restrict__ V){
  __shared__ float a[8][ND];
  const int t = threadIdx.x;
  const int m0 = blockIdx.x*8;
  #pragma unroll
  for(int r=0;r<8;r++) a[r][t] = src[(size_t)(m0+r)*ND + t];
  __syncthreads();
  float aq[8], ak[8], av[8];
  #pragma unroll
  for(int r=0;r<8;r++){ aq[r]=bq[t]; ak[r]=bk[t]; av[r]=bv[t]; }
  const float4* wq = (const float4*)(Wq + (size_t)t*ND);
  const float4* wk = (const float4*)(Wk + (size_t)t*ND);
  const float4* wv = (const float4*)(Wv + (size_t)t*ND);
  for(int k4=0;k4<ND/4;k4++){
    float4 q4 = wq[k4], k4v = wk[k4], v4 = wv[k4];
    #pragma unroll
    for(int r=0;r<8;r++){
      float4 a4 = *(const float4*)&a[r][k4*4];
      aq[r] += a4.x*q4.x + a4.y*q4.y + a4.z*q4.z + a4.w*q4.w;
      ak[r] += a4.x*k4v.x + a4.y*k4v.y + a4.z*k4v.z + a4.w*k4v.w;
      av[r] += a4.x*v4.x + a4.y*v4.y + a4.z*v4.z + a4.w*v4.w;
    }
  }
  #pragma unroll
  for(int r=0;r<8;r++){
    size_t o = (size_t)(m0+r)*ND + t;
    Q[o]=f2bf(aq[r]*QSCALE); K[o]=f2bf(ak[r]); V[o]=f2bf(av[r]);
  }
}

// ---------------- MFMA flash attention (bf16), 4 waves x 16 queries per block ----------------
__global__ __launch_bounds__(256) void attn_kernel(
    const unsigned short* __restrict__ Q, const unsigned short* __restrict__ K,
    const unsigned short* __restrict__ V, float* __restrict__ AO){
  __shared__ unsigned short Klds[64*KPAD];    // 5120 B   [key][d] rows of 40
  __shared__ unsigned short Vt[32*VTP];       // 4608 B   [d][key] rows of 72
  __shared__ unsigned short Plds[4][16*VTP];  // 9216 B   per-wave [q][key] rows of 72
  __shared__ float Olds[4*16*36];             // 9216 B   per-wave O bounce

  const int t  = threadIdx.x;
  const int l  = t & 63;
  const int wv = t >> 6;
  const int lx = l & 15, lw = l >> 4;

  const int bid = blockIdx.x;
  const int qt  = 31 - (bid >> 5);           // biggest query tiles first
  const int bh  = bid & 31;
  const int b = bh >> 3, h = bh & 7;
  const int qbase = qt * 64;
  const int qg = qbase + wv*16 + lx;         // this lane's query row

  // Q fragment (B operand of QK^T): lane holds Q[qg][8*lw .. +7], pre-scaled
  short8v qf = *(const short8v*)(Q + ((size_t)(b*NS + qg))*ND + h*NHD + 8*lw);

  f32x4 accL = {0.f,0.f,0.f,0.f}, accH = {0.f,0.f,0.f,0.f};   // O^T accum (d 0-15 / 16-31)
  float m = -INFINITY, lsum = 0.f;

  const unsigned short* Kg = K + ((size_t)b*NS)*ND + h*NHD;
  const unsigned short* Vg = V + ((size_t)b*NS)*ND + h*NHD;

  const int jmax  = qbase + 63;
  const int wqmax = qbase + wv*16 + 15;
  const int row = t >> 2, part = t & 3;      // staging role: 64 rows x 4x8 elems

  // prefetch tile 0 into regs
  short8v kst = *(const short8v*)(Kg + (size_t)row*ND + part*8);
  short8v vst = *(const short8v*)(Vg + (size_t)row*ND + part*8);

  unsigned short* pw = &Plds[wv][lx*VTP];

  for (int jt = 0; jt <= jmax; jt += 64){
    __syncthreads();
    *(short8v*)(Klds + row*KPAD + part*8) = kst;
    #pragma unroll
    for (int j=0;j<8;j++) Vt[(8*part + j)*VTP + row] = (unsigned short)vst[j];
    __syncthreads();
    if (jt + 64 <= jmax){     // prefetch next tile under compute
      kst = *(const short8v*)(Kg + (size_t)(jt+64+row)*ND + part*8);
      vst = *(const short8v*)(Vg + (size_t)(jt+64+row)*ND + part*8);
    }
    if (jt <= wqmax){
      // ---- QK^T (swapped): S^T[key][q], 4 key-blocks of 16
      f32x4 s4[4];
      #pragma unroll
      for (int kb=0; kb<4; kb++){
        short8v kf = *(const short8v*)(Klds + (kb*16 + lx)*KPAD + 8*lw);
        f32x4 z = {0.f,0.f,0.f,0.f};
        s4[kb] = __builtin_amdgcn_mfma_f32_16x16x32_bf16(kf, qf, z, 0,0,0);
      }
      // ---- mask + online softmax (per-row state replicated over 4 lanes, q = lx)
      const bool needmask = (jt + 63) > (qbase + wv*16);
      const int keyb = jt + 4*lw;
      float sv[16];
      float smax = -INFINITY;
      #pragma unroll
      for (int kb=0;kb<4;kb++){
        #pragma unroll
        for (int r=0;r<4;r++){
          float x = s4[kb][r];
          if (needmask && (keyb + kb*16 + r) > qg) x = -INFINITY;
          sv[kb*4+r] = x;
          smax = fmaxf(smax, x);
        }
      }
      smax = fmaxf(smax, __shfl_xor(smax, 16));
      smax = fmaxf(smax, __shfl_xor(smax, 32));
      float mn = fmaxf(m, smax);
      float sc = exp2f(m - mn);       // first tile: exp2(-inf)=0
      m = mn;
      float pv[16]; float ps = 0.f;
      #pragma unroll
      for (int i2=0;i2<16;i2++){ pv[i2] = exp2f(sv[i2] - mn); ps += pv[i2]; }
      lsum = lsum * sc + ps;
      accL *= sc; accH *= sc;
      // ---- write P (bf16) to per-wave LDS in [q][key] layout: 4x ds_write_b64
      #pragma unroll
      for (int kb=0;kb<4;kb++){
        short4v pk;
        #pragma unroll
        for (int r=0;r<4;r++) pk[r] = (short)f2bf(pv[kb*4+r]);
        *(short4v*)(pw + 16*kb + 4*lw) = pk;
      }
      // ---- PV (swapped): O^T += V^T-frag @ P^T-frag, per 32-key chunk
      #pragma unroll
      for (int c=0;c<2;c++){
        short8v pf = *(const short8v*)(&Plds[wv][lx*VTP] + 32*c + 8*lw);          // B: P^T[k][q=lx]
        short8v aL = *(const short8v*)(&Vt[lx*VTP]       + 32*c + 8*lw);          // A: V^T[d=lx][k]
        short8v aH = *(const short8v*)(&Vt[(16+lx)*VTP]  + 32*c + 8*lw);          // A: d=16+lx
        accL = __builtin_amdgcn_mfma_f32_16x16x32_bf16(aL, pf, accL, 0,0,0);
        accH = __builtin_amdgcn_mfma_f32_16x16x32_bf16(aH, pf, accH, 0,0,0);
      }
    }
  }
  // ---- epilogue: normalize, bounce O^T through LDS, coalesced store
  float lt = lsum + __shfl_xor(lsum, 16);
  lt += __shfl_xor(lt, 32);
  float inv = 1.f / lt;
  float* ol = &Olds[wv*576];
  #pragma unroll
  for (int r=0;r<4;r++){
    ol[lx*36 +      4*lw + r] = accL[r]*inv;
    ol[lx*36 + 16 + 4*lw + r] = accH[r]*inv;
  }
  __syncthreads();
  float* aop = AO + ((size_t)(b*NS + qbase + wv*16))*ND + h*NHD;
  #pragma unroll
  for (int it=0; it<2; it++){
    int task = it*64 + l;            // 128 tasks: 16 rows x 8 float4 chunks
    int rr = task >> 3, cc = task & 7;
    f32x4 val = *(const f32x4*)&ol[rr*36 + cc*4];
    *(f32x4*)(aop + (size_t)rr*ND + cc*4) = val;
  }
}

// ---------------- O-projection + residual + LayerNorm1 ----------------
__global__ __launch_bounds__(256) void oln_kernel(
    const float* __restrict__ AO, const float* __restrict__ Wo, const float* __restrict__ bo,
    const float* __restrict__ src, const float* __restrict__ g1, const float* __restrict__ be1,
    float* __restrict__ S2){
  __shared__ float a[16][ND];
  __shared__ float c[16][ND];
  const int t = threadIdx.x;
  const int m0 = blockIdx.x*16;
  #pragma unroll
  for(int r=0;r<16;r++) a[r][t] = AO[(size_t)(m0+r)*ND + t];
  __syncthreads();
  float acc[16];
  #pragma unroll
  for(int r=0;r<16;r++) acc[r] = bo[t];
  const float4* w = (const float4*)(Wo + (size_t)t*ND);
  for(int k4=0;k4<ND/4;k4++){
    float4 w4 = w[k4];
    #pragma unroll
    for(int r=0;r<16;r++){
      float4 a4 = *(const float4*)&a[r][k4*4];
      acc[r] += a4.x*w4.x + a4.y*w4.y + a4.z*w4.z + a4.w*w4.w;
    }
  }
  #pragma unroll
  for(int r=0;r<16;r++) c[r][t] = acc[r] + src[(size_t)(m0+r)*ND + t];
  __syncthreads();
  const int lane = t&63, wv_ = t>>6;
  #pragma unroll
  for(int rr=0; rr<4; rr++){
    int r = wv_*4+rr;
    float x[4]; float s=0.f, qq=0.f;
    #pragma unroll
    for(int k=0;k<4;k++){ x[k]=c[r][lane+64*k]; s+=x[k]; qq+=x[k]*x[k]; }
    s = wsum(s); qq = wsum(qq);
    float mean = s*(1.f/ND);
    float var = qq*(1.f/ND) - mean*mean;
    float rstd = rsqrtf(var + 1e-5f);
    #pragma unroll
    for(int k=0;k<4;k++){
      int col = lane+64*k;
      S2[(size_t)(m0+r)*ND+col] = (x[k]-mean)*rstd*g1[col] + be1[col];
    }
  }
}

// ---------------- FFN1 + exact GELU ----------------
__global__ __launch_bounds__(256) void ffn1_kernel(
    const float* __restrict__ S2, const float* __restrict__ W1, const float* __restrict__ b1,
    float* __restrict__ FFo){
  __shared__ float a[16][ND];
  const int t = threadIdx.x;
  const int m0 = blockIdx.x*16;
  #pragma unroll
  for(int r=0;r<16;r++) a[r][t] = S2[(size_t)(m0+r)*ND + t];
  __syncthreads();
  float acc[4][16];
  #pragma unroll
  for(int cc=0;cc<4;cc++){
    float bb = b1[t + 256*cc];
    #pragma unroll
    for(int r=0;r<16;r++) acc[cc][r] = bb;
  }
  const float4* w0 = (const float4*)(W1 + (size_t)(t+  0)*ND);
  const float4* w1 = (const float4*)(W1 + (size_t)(t+256)*ND);
  const float4* w2 = (const float4*)(W1 + (size_t)(t+512)*ND);
  const float4* w3 = (const float4*)(W1 + (size_t)(t+768)*ND);
  for(int k4=0;k4<ND/4;k4++){
    float4 c0=w0[k4], c1=w1[k4], c2=w2[k4], c3=w3[k4];
    #pragma unroll
    for(int r=0;r<16;r++){
      float4 a4 = *(const float4*)&a[r][k4*4];
      acc[0][r] += a4.x*c0.x + a4.y*c0.y + a4.z*c0.z + a4.w*c0.w;
      acc[1][r] += a4.x*c1.x + a4.y*c1.y + a4.z*c1.z + a4.w*c1.w;
      acc[2][r] += a4.x*c2.x + a4.y*c2.y + a4.z*c2.z + a4.w*c2.w;
      acc[3][r] += a4.x*c3.x + a4.y*c3.y + a4.z*c3.z + a4.w*c3.w;
    }
  }
  #pragma unroll
  for(int cc=0;cc<4;cc++){
    int col = t + 256*cc;
    #pragma unroll
    for(int r=0;r<16;r++){
      float x = acc[cc][r];
      FFo[(size_t)(m0+r)*NFF + col] = 0.5f*x*(1.f+erff(x*0.70710678118654752f));
    }
  }
}

// ---------------- FFN2 + residual + LayerNorm2 ----------------
__global__ __launch_bounds__(256) void ffn2_kernel(
    const float* __restrict__ FFo, const float* __restrict__ W2, const float* __restrict__ b2,
    const float* __restrict__ S2, const float* __restrict__ g2, const float* __restrict__ be2,
    float* __restrict__ out){
  __shared__ float a[16][ND];
  __shared__ float c[16][ND];
  const int t = threadIdx.x;
  const int m0 = blockIdx.x*16;
  float acc[16];
  #pragma unroll
  for(int r=0;r<16;r++) acc[r] = b2[t];
  for(int kc=0; kc<4; kc++){
    __syncthreads();
    #pragma unroll
    for(int r=0;r<16;r++) a[r][t] = FFo[(size_t)(m0+r)*NFF + kc*256 + t];
    __syncthreads();
    const float4* w = (const float4*)(W2 + (size_t)t*NFF + kc*256);
    for(int k4=0;k4<64;k4++){
      float4 w4 = w[k4];
      #pragma unroll
      for(int r=0;r<16;r++){
        float4 a4 = *(const float4*)&a[r][k4*4];
        acc[r] += a4.x*w4.x + a4.y*w4.y + a4.z*w4.z + a4.w*w4.w;
      }
    }
  }
  #pragma unroll
  for(int r=0;r<16;r++) c[r][t] = acc[r] + S2[(size_t)(m0+r)*ND + t];
  __syncthreads();
  const int lane = t&63, wv_ = t>>6;
  #pragma unroll
  for(int rr=0; rr<4; rr++){
    int r = wv_*4+rr;
    float x[4]; float s=0.f, qq=0.f;
    #pragma unroll
    for(int k=0;k<4;k++){ x[k]=c[r][lane+64*k]; s+=x[k]; qq+=x[k]*x[k]; }
    s = wsum(s); qq = wsum(qq);
    float mean = s*(1.f/ND);
    float var = qq*(1.f/ND) - mean*mean;
    float rstd = rsqrtf(var + 1e-5f);
    #pragma unroll
    for(int k=0;k<4;k++){
      int col = lane+64*k;
      out[(size_t)(m0+r)*ND+col] = (x[k]-mean)*rstd*g2[col] + be2[col];
    }
  }
}

extern "C" void kernel_launch(void* const* d_in, const int* in_sizes, int n_in,
                              void* d_out, int out_size, void* d_ws, size_t ws_size,
                              hipStream_t stream){
  const float* src = (const float*)d_in[0];
  const float* Wq  = (const float*)d_in[1];
  const float* bq  = (const float*)d_in[2];
  const float* Wk  = (const float*)d_in[3];
  const float* bk  = (const float*)d_in[4];
  const float* Wv  = (const float*)d_in[5];
  const float* bv  = (const float*)d_in[6];
  const float* Wo  = (const float*)d_in[7];
  const float* bo  = (const float*)d_in[8];
  const float* W1  = (const float*)d_in[9];
  const float* b1  = (const float*)d_in[10];
  const float* W2  = (const float*)d_in[11];
  const float* b2  = (const float*)d_in[12];
  const float* g1  = (const float*)d_in[13];
  const float* be1 = (const float*)d_in[14];
  const float* g2  = (const float*)d_in[15];
  const float* be2 = (const float*)d_in[16];
  // len_m1 (d_in[17]) is redundant: the prefix-global mask is implied by causal.

  const size_t SZ = (size_t)NM*ND;
  unsigned short* Qw = (unsigned short*)d_ws;
  unsigned short* Kw = Qw + SZ;
  unsigned short* Vw = Kw + SZ;
  float* AO = (float*)(Vw + SZ);
  float* S2 = AO + SZ;
  float* FF = S2 + SZ;
  float* out = (float*)d_out;

  qkv_kernel <<<NM/8, 256, 0, stream>>>(src, Wq,bq, Wk,bk, Wv,bv, Qw,Kw,Vw);
  attn_kernel<<<NB*NH*(NS/64), 256, 0, stream>>>(Qw, Kw, Vw, AO);
  oln_kernel <<<NM/16, 256, 0, stream>>>(AO, Wo, bo, src, g1, be1, S2);
  ffn1_kernel<<<NM/16, 256, 0, stream>>>(S2, W1, b1, FF);
  ffn2_kernel<<<NM/16, 256, 0, stream>>>(FF, W2, b2, S2, g2, be2, out);
}

// Round 4
// 123.524 us; speedup vs baseline: 7.9332x; 4.1611x over previous
//
#include <hip/hip_runtime.h>
#include <math.h>

#define NB 4
#define NS 2048
#define ND 256
#define NH 8
#define NHD 32
#define NFF 1024
#define NM (NB*NS)   // 8192
#define KPAD 40      // bf16 elems per K-tile row in LDS (80B stride)
#define VTP 72       // Vt/Plds row stride in bf16 elems
#define AS 264       // gemm A-tile LDS row stride (bf16 elems)
// qkv Q pre-scale: (1/sqrt(32)) * log2(e)  -> softmax uses exp2
#define QSCALE 0.2550181657f

typedef __attribute__((ext_vector_type(4))) short short4v;
typedef __attribute__((ext_vector_type(8))) short short8v;
typedef __attribute__((ext_vector_type(4))) float f32x4;
typedef unsigned short us;

__device__ __forceinline__ us f2bf(float f){
  union { float f; unsigned u; } c; c.f = f;
  unsigned u = c.u + 0x7fffu + ((c.u >> 16) & 1u);   // RNE
  return (us)(u >> 16);
}

__device__ __forceinline__ float wsum(float v){
  #pragma unroll
  for(int o=32;o>0;o>>=1) v += __shfl_xor(v,o);
  return v;
}

// ---------------- prep: fp32 -> bf16 conversions (src + all weights, Wq/bq pre-scaled) ----------------
__global__ __launch_bounds__(256) void prep_kernel(
    const float* __restrict__ src,
    const float* __restrict__ Wq, const float* __restrict__ Wk, const float* __restrict__ Wv,
    const float* __restrict__ Wo, const float* __restrict__ W1, const float* __restrict__ W2,
    const float* __restrict__ bq,
    us* __restrict__ X, us* __restrict__ Wqkvb, us* __restrict__ Wob,
    us* __restrict__ W1b, us* __restrict__ W2b, float* __restrict__ bqs){
  unsigned bid = blockIdx.x;
  if (bid == 1408){ bqs[threadIdx.x] = bq[threadIdx.x]*QSCALE; return; }
  unsigned u = bid*256u + threadIdx.x;     // 8-elem unit
  const float* sp; us* dp; float sc = 1.f;
  if (u < 262144u){ sp = src + (size_t)u*8; dp = X + (size_t)u*8; }
  else {
    unsigned v = u - 262144u;
    if      (v <  8192u){ sp = Wq + (size_t)v*8;            dp = Wqkvb + (size_t)v*8;            sc = QSCALE; }
    else if (v < 16384u){ sp = Wk + (size_t)(v- 8192u)*8;   dp = Wqkvb + 65536 + (size_t)(v- 8192u)*8; }
    else if (v < 24576u){ sp = Wv + (size_t)(v-16384u)*8;   dp = Wqkvb + 131072 + (size_t)(v-16384u)*8; }
    else if (v < 32768u){ sp = Wo + (size_t)(v-24576u)*8;   dp = Wob + (size_t)(v-24576u)*8; }
    else if (v < 65536u){ sp = W1 + (size_t)(v-32768u)*8;   dp = W1b + (size_t)(v-32768u)*8; }
    else               { sp = W2 + (size_t)(v-65536u)*8;    dp = W2b + (size_t)(v-65536u)*8; }
  }
  float4 a = *(const float4*)sp, b = *(const float4*)(sp+4);
  short8v o;
  o[0]=(short)f2bf(a.x*sc); o[1]=(short)f2bf(a.y*sc); o[2]=(short)f2bf(a.z*sc); o[3]=(short)f2bf(a.w*sc);
  o[4]=(short)f2bf(b.x*sc); o[5]=(short)f2bf(b.y*sc); o[6]=(short)f2bf(b.z*sc); o[7]=(short)f2bf(b.w*sc);
  *(short8v*)dp = o;
}

// ---------------- generic MFMA GEMM: C[M][N] = A[M][KTOT] @ W[N][KTOT]^T (+bias, epilogue) ----------------
// tile: M=64 x N=128 per block (4 waves, each 64x32). EPI: 0=qkv->bf16x3, 1=resid->f32, 2=gelu->bf16, 3=resid->f32
template<int KTOT, int EPI>
__global__ __launch_bounds__(256) void gemm_kernel(
    const us* __restrict__ A, const us* __restrict__ W,
    const float* __restrict__ bias0, const float* __restrict__ bias1, const float* __restrict__ bias2,
    const float* __restrict__ resid,
    us* __restrict__ outb, float* __restrict__ outf){
  __shared__ us Asl[64*AS];
  const int t = threadIdx.x, l = t&63, wv = t>>6;
  const int lx = l&15, lw = l>>4;
  const int m0 = blockIdx.y*64;
  const int n0 = blockIdx.x*128 + wv*32;

  f32x4 acc[4][2];
  #pragma unroll
  for(int mb=0;mb<4;mb++)
    #pragma unroll
    for(int nb=0;nb<2;nb++) acc[mb][nb] = (f32x4){0.f,0.f,0.f,0.f};

  for (int kc = 0; kc < KTOT; kc += 256){
    __syncthreads();
    #pragma unroll
    for (int it=0; it<8; it++){
      int idx = it*256 + t;            // 2048 16B-units: 64 rows x 32
      int r = idx>>5, c = idx&31;
      *(short8v*)&Asl[r*AS + c*8] = *(const short8v*)(A + (size_t)(m0+r)*KTOT + kc + c*8);
    }
    __syncthreads();
    short8v bf[2][8];
    #pragma unroll
    for (int nb=0; nb<2; nb++)
      #pragma unroll
      for (int ks=0; ks<8; ks++)
        bf[nb][ks] = *(const short8v*)(W + (size_t)(n0 + nb*16 + lx)*KTOT + kc + ks*32 + 8*lw);
    #pragma unroll
    for (int ks=0; ks<8; ks++){
      short8v af[4];
      #pragma unroll
      for (int mb=0; mb<4; mb++)
        af[mb] = *(const short8v*)&Asl[(mb*16+lx)*AS + ks*32 + 8*lw];
      #pragma unroll
      for (int mb=0; mb<4; mb++){
        acc[mb][0] = __builtin_amdgcn_mfma_f32_16x16x32_bf16(af[mb], bf[0][ks], acc[mb][0], 0,0,0);
        acc[mb][1] = __builtin_amdgcn_mfma_f32_16x16x32_bf16(af[mb], bf[1][ks], acc[mb][1], 0,0,0);
      }
    }
  }
  // epilogue: lane l, reg r -> m = m0 + mb*16 + 4*lw + r, n = n0 + nb*16 + lx
  const int mr0 = m0 + 4*lw;
  #pragma unroll
  for (int nb=0; nb<2; nb++){
    int n = n0 + nb*16 + lx;
    if (EPI == 0){
      int seg = n >> 8, nn = n & 255;
      const float* bp = (seg==0) ? bias0 : (seg==1) ? bias1 : bias2;
      float bb = bp[nn];
      us* op = outb + (size_t)seg*((size_t)NM*ND) + nn;
      #pragma unroll
      for (int mb=0; mb<4; mb++)
        #pragma unroll
        for (int r=0; r<4; r++)
          op[(size_t)(mr0 + mb*16 + r)*ND] = f2bf(acc[mb][nb][r] + bb);
    } else if (EPI == 1 || EPI == 3){
      float bb = bias0[n];
      #pragma unroll
      for (int mb=0; mb<4; mb++)
        #pragma unroll
        for (int r=0; r<4; r++){
          size_t off = (size_t)(mr0 + mb*16 + r)*ND + n;
          outf[off] = acc[mb][nb][r] + bb + resid[off];
        }
    } else {  // EPI 2: gelu -> bf16, stride NFF
      float bb = bias0[n];
      #pragma unroll
      for (int mb=0; mb<4; mb++)
        #pragma unroll
        for (int r=0; r<4; r++){
          float x = acc[mb][nb][r] + bb;
          float g = 0.5f*x*(1.f + erff(x*0.70710678118654752f));
          outb[(size_t)(mr0 + mb*16 + r)*NFF + n] = f2bf(g);
        }
    }
  }
}

// ---------------- standalone LayerNorm: fp32 in -> bf16 (optional) + fp32 (optional) ----------------
__global__ __launch_bounds__(256) void ln_kernel(
    const float* __restrict__ Xin, const float* __restrict__ g, const float* __restrict__ be,
    us* __restrict__ outb, float* __restrict__ outf){
  const int t = threadIdx.x, lane = t&63, wv = t>>6;
  const int m0 = blockIdx.x*16;
  #pragma unroll
  for(int rr=0; rr<4; rr++){
    int r = m0 + wv*4 + rr;
    const float* xr = Xin + (size_t)r*ND;
    float x[4]; float s=0.f,q=0.f;
    #pragma unroll
    for(int k=0;k<4;k++){ x[k]=xr[lane+64*k]; s+=x[k]; q+=x[k]*x[k]; }
    s = wsum(s); q = wsum(q);
    float mean = s*(1.f/ND), var = q*(1.f/ND)-mean*mean;
    float rstd = rsqrtf(var+1e-5f);
    #pragma unroll
    for(int k=0;k<4;k++){
      int col = lane+64*k;
      float y = (x[k]-mean)*rstd*g[col] + be[col];
      if (outf) outf[(size_t)r*ND+col] = y;
      if (outb) outb[(size_t)r*ND+col] = f2bf(y);
    }
  }
}

// ---------------- MFMA flash attention (bf16), 4 waves x 16 queries per block ----------------
__global__ __launch_bounds__(256) void attn_kernel(
    const us* __restrict__ Q, const us* __restrict__ K,
    const us* __restrict__ V, us* __restrict__ AO){
  __shared__ us Klds[64*KPAD];         // [key][d] rows of 40
  __shared__ us Vt[32*VTP];            // [d][key] rows of 72
  __shared__ us Plds[4][16*VTP];       // per-wave [q][key] rows of 72
  __shared__ float Olds[4*16*36];      // per-wave O bounce

  const int t  = threadIdx.x;
  const int l  = t & 63;
  const int wv = t >> 6;
  const int lx = l & 15, lw = l >> 4;

  const int bid = blockIdx.x;
  const int qt  = 31 - (bid >> 5);           // biggest query tiles first
  const int bh  = bid & 31;
  const int b = bh >> 3, h = bh & 7;
  const int qbase = qt * 64;
  const int qg = qbase + wv*16 + lx;

  short8v qf = *(const short8v*)(Q + ((size_t)(b*NS + qg))*ND + h*NHD + 8*lw);

  f32x4 accL = {0.f,0.f,0.f,0.f}, accH = {0.f,0.f,0.f,0.f};
  float m = -INFINITY, lsum = 0.f;

  const us* Kg = K + ((size_t)b*NS)*ND + h*NHD;
  const us* Vg = V + ((size_t)b*NS)*ND + h*NHD;

  const int jmax  = qbase + 63;
  const int wqmax = qbase + wv*16 + 15;
  const int row = t >> 2, part = t & 3;

  short8v kst = *(const short8v*)(Kg + (size_t)row*ND + part*8);
  short8v vst = *(const short8v*)(Vg + (size_t)row*ND + part*8);

  us* pw = &Plds[wv][lx*VTP];

  for (int jt = 0; jt <= jmax; jt += 64){
    __syncthreads();
    *(short8v*)(Klds + row*KPAD + part*8) = kst;
    #pragma unroll
    for (int j=0;j<8;j++) Vt[(8*part + j)*VTP + row] = (us)vst[j];
    __syncthreads();
    if (jt + 64 <= jmax){
      kst = *(const short8v*)(Kg + (size_t)(jt+64+row)*ND + part*8);
      vst = *(const short8v*)(Vg + (size_t)(jt+64+row)*ND + part*8);
    }
    if (jt <= wqmax){
      f32x4 s4[4];
      #pragma unroll
      for (int kb=0; kb<4; kb++){
        short8v kf = *(const short8v*)(Klds + (kb*16 + lx)*KPAD + 8*lw);
        f32x4 z = {0.f,0.f,0.f,0.f};
        s4[kb] = __builtin_amdgcn_mfma_f32_16x16x32_bf16(kf, qf, z, 0,0,0);
      }
      const bool needmask = (jt + 63) > (qbase + wv*16);
      const int keyb = jt + 4*lw;
      float sv[16];
      float smax = -INFINITY;
      #pragma unroll
      for (int kb=0;kb<4;kb++){
        #pragma unroll
        for (int r=0;r<4;r++){
          float x = s4[kb][r];
          if (needmask && (keyb + kb*16 + r) > qg) x = -INFINITY;
          sv[kb*4+r] = x;
          smax = fmaxf(smax, x);
        }
      }
      smax = fmaxf(smax, __shfl_xor(smax, 16));
      smax = fmaxf(smax, __shfl_xor(smax, 32));
      float mn = fmaxf(m, smax);
      float sc = exp2f(m - mn);
      m = mn;
      float pv[16]; float ps = 0.f;
      #pragma unroll
      for (int i2=0;i2<16;i2++){ pv[i2] = exp2f(sv[i2] - mn); ps += pv[i2]; }
      lsum = lsum * sc + ps;
      accL *= sc; accH *= sc;
      #pragma unroll
      for (int kb=0;kb<4;kb++){
        short4v pk;
        #pragma unroll
        for (int r=0;r<4;r++) pk[r] = (short)f2bf(pv[kb*4+r]);
        *(short4v*)(pw + 16*kb + 4*lw) = pk;
      }
      #pragma unroll
      for (int c=0;c<2;c++){
        short8v pf = *(const short8v*)(&Plds[wv][lx*VTP] + 32*c + 8*lw);
        short8v aL = *(const short8v*)(&Vt[lx*VTP]       + 32*c + 8*lw);
        short8v aH = *(const short8v*)(&Vt[(16+lx)*VTP]  + 32*c + 8*lw);
        accL = __builtin_amdgcn_mfma_f32_16x16x32_bf16(aL, pf, accL, 0,0,0);
        accH = __builtin_amdgcn_mfma_f32_16x16x32_bf16(aH, pf, accH, 0,0,0);
      }
    }
  }
  float lt = lsum + __shfl_xor(lsum, 16);
  lt += __shfl_xor(lt, 32);
  float inv = 1.f / lt;
  float* ol = &Olds[wv*576];
  #pragma unroll
  for (int r=0;r<4;r++){
    ol[lx*36 +      4*lw + r] = accL[r]*inv;
    ol[lx*36 + 16 + 4*lw + r] = accH[r]*inv;
  }
  __syncthreads();
  {
    int rr = l >> 2, cc = l & 3;             // 16 rows x 4 chunks of 8
    const float* o8p = &ol[rr*36 + cc*8];
    short8v o8;
    #pragma unroll
    for (int j=0;j<8;j++) o8[j] = (short)f2bf(o8p[j]);
    us* aop = AO + ((size_t)(b*NS + qbase + wv*16 + rr))*ND + h*NHD + cc*8;
    *(short8v*)aop = o8;
  }
}

extern "C" void kernel_launch(void* const* d_in, const int* in_sizes, int n_in,
                              void* d_out, int out_size, void* d_ws, size_t ws_size,
                              hipStream_t stream){
  const float* src = (const float*)d_in[0];
  const float* Wq  = (const float*)d_in[1];
  const float* bq  = (const float*)d_in[2];
  const float* Wk  = (const float*)d_in[3];
  const float* bk  = (const float*)d_in[4];
  const float* Wv  = (const float*)d_in[5];
  const float* bv  = (const float*)d_in[6];
  const float* Wo  = (const float*)d_in[7];
  const float* bo  = (const float*)d_in[8];
  const float* W1  = (const float*)d_in[9];
  const float* b1  = (const float*)d_in[10];
  const float* W2  = (const float*)d_in[11];
  const float* b2  = (const float*)d_in[12];
  const float* g1  = (const float*)d_in[13];
  const float* be1 = (const float*)d_in[14];
  const float* g2  = (const float*)d_in[15];
  const float* be2 = (const float*)d_in[16];
  // len_m1 (d_in[17]) is redundant: the prefix-global mask is implied by causal.

  const size_t MB = 1048576;
  unsigned char* w8 = (unsigned char*)d_ws;
  us* X     = (us*)(w8 + 0);           // 4MB, dead after gemm_qkv
  us* Qb    = (us*)(w8 + 4*MB);        // 4MB, dead after attn
  us* Kb    = (us*)(w8 + 8*MB);
  us* Vb    = (us*)(w8 + 12*MB);
  us* AO    = (us*)(w8 + 16*MB);
  us* S2b   = (us*)(w8 + 20*MB);
  us* FF    = (us*)(w8 + 24*MB);       // 16MB
  us* Wqkvb = (us*)(w8 + 40*MB);       // 384KB  (rows 0-255 Wq*QSCALE | Wk | Wv)
  us* Wob   = (us*)(w8 + 40*MB + 384*1024);
  us* W1b   = (us*)(w8 + 40*MB + 512*1024);
  us* W2b   = (us*)(w8 + 40*MB + 1024*1024);
  float* bqs   = (float*)(w8 + 40*MB + 1536*1024);
  float* S2pre = (float*)(w8 + 42*MB); // 8MB
  float* S2f   = (float*)(w8 + 50*MB); // 8MB
  float* Ypre  = (float*)(w8 + 0);     // 8MB, aliases X+Qb (both dead by then)
  float* out = (float*)d_out;

  prep_kernel<<<1409, 256, 0, stream>>>(src, Wq,Wk,Wv,Wo,W1,W2, bq,
                                        X, Wqkvb, Wob, W1b, W2b, bqs);
  gemm_kernel<256,0><<<dim3(6,128), 256, 0, stream>>>(X, Wqkvb, bqs, bk, bv, nullptr, Qb, nullptr);
  attn_kernel<<<NB*NH*(NS/64), 256, 0, stream>>>(Qb, Kb, Vb, AO);
  gemm_kernel<256,1><<<dim3(2,128), 256, 0, stream>>>(AO, Wob, bo, nullptr, nullptr, src, nullptr, S2pre);
  ln_kernel<<<NM/16, 256, 0, stream>>>(S2pre, g1, be1, S2b, S2f);
  gemm_kernel<256,2><<<dim3(8,128), 256, 0, stream>>>(S2b, W1b, b1, nullptr, nullptr, nullptr, FF, nullptr);
  gemm_kernel<1024,3><<<dim3(2,128), 256, 0, stream>>>(FF, W2b, b2, nullptr, nullptr, S2f, nullptr, Ypre);
  ln_kernel<<<NM/16, 256, 0, stream>>>(Ypre, g2, be2, nullptr, out);
}